// Round 7
// baseline (1164.595 us; speedup 1.0000x reference)
//
#include <hip/hip_runtime.h>
#include <math.h>

#define Bc 2
#define Ec 100000
#define Vc 12500
#define Dc 128
#define Lc 4

typedef __attribute__((ext_vector_type(4))) float f32x4;
typedef __attribute__((ext_vector_type(8))) short short8s;
typedef __attribute__((ext_vector_type(8))) __bf16 bf16x8;

static __device__ __forceinline__ short f2bf(float f) {
    unsigned u = __builtin_bit_cast(unsigned, f);
    unsigned r = (u + 0x7FFFu + ((u >> 16) & 1u)) >> 16;  // RNE
    return (short)r;
}

static __device__ __forceinline__ f32x4 mfma16(short8s a, short8s b, f32x4 c) {
    return __builtin_amdgcn_mfma_f32_16x16x32_bf16(
        __builtin_bit_cast(bf16x8, a), __builtin_bit_cast(bf16x8, b), c, 0, 0, 0);
}

// ---------------- timestep embedding MLP (tiny: B=2) ----------------
__global__ void t_emb_kernel(const int* __restrict__ n,
                             const float* __restrict__ te_w1, const float* __restrict__ te_b1,
                             const float* __restrict__ te_w2, const float* __restrict__ te_b2,
                             float* __restrict__ t_emb) {
    const int b = blockIdx.x;
    const int t = threadIdx.x; // 128 threads
    __shared__ float emb[Dc];
    __shared__ float hid[4 * Dc];
    const float nf = (float)n[b];
    const int half = Dc / 2;
    {
        int j = (t < half) ? t : (t - half);
        float freq = expf(-logf(10000.0f) * (float)j / (float)half);
        float arg = nf * freq;
        emb[t] = (t < half) ? sinf(arg) : cosf(arg);
    }
    __syncthreads();
    for (int jj = 0; jj < 4; ++jj) {
        int c = t + jj * Dc;
        float acc = te_b1[c];
        for (int k = 0; k < Dc; ++k) acc += emb[k] * te_w1[k * (4 * Dc) + c];
        hid[c] = acc / (1.0f + expf(-acc));
    }
    __syncthreads();
    float acc = te_b2[t];
    for (int k = 0; k < 4 * Dc; ++k) acc += hid[k] * te_w2[k * Dc + t];
    t_emb[b * Dc + t] = acc;
}

// ---------------- input projection + t_emb add ----------------
__global__ void input_proj_kernel(const float* __restrict__ delta,
                                  const float* __restrict__ w_in, const float* __restrict__ b_in,
                                  const float* __restrict__ t_emb,
                                  float* __restrict__ h) {
    int idx = blockIdx.x * blockDim.x + threadIdx.x;
    const int total = Bc * Ec * (Dc / 4);
    if (idx >= total) return;
    int dq = idx & (Dc / 4 - 1);
    int be = idx >> 5;
    int b = be / Ec;
    const float* dd = delta + (size_t)be * 3;
    float d0 = dd[0], d1 = dd[1], d2 = dd[2];
    float4 acc = ((const float4*)b_in)[dq];
    float4 te = ((const float4*)t_emb)[b * (Dc / 4) + dq];
    float4 w0 = ((const float4*)w_in)[dq];
    float4 w1 = ((const float4*)w_in)[(Dc / 4) + dq];
    float4 w2 = ((const float4*)w_in)[2 * (Dc / 4) + dq];
    acc.x += te.x + d0 * w0.x + d1 * w1.x + d2 * w2.x;
    acc.y += te.y + d0 * w0.y + d1 * w1.y + d2 * w2.y;
    acc.z += te.z + d0 * w0.z + d1 * w1.z + d2 * w2.z;
    acc.w += te.w + d0 * w0.w + d1 * w1.w + d2 * w2.w;
    ((float4*)h)[idx] = acc;
}

// ---------------- weight pre-convert: fp32 -> bf16 transposed ----------------
__global__ void convert_w_kernel(const float* __restrict__ W1, const float* __restrict__ W2,
                                 short* __restrict__ w1t, short* __restrict__ w2t) {
    int idx = blockIdx.x * blockDim.x + threadIdx.x;
    if (idx < Lc * 128 * 256) {
        int l = idx / (128 * 256);
        int r = idx - l * (128 * 256);
        int nn = r >> 8;          // 0..127
        int k = r & 255;          // 0..255
        w1t[idx] = f2bf(W1[(size_t)l * 256 * 128 + k * 128 + nn]);
    }
    if (idx < Lc * 128 * 128) {
        int l = idx / (128 * 128);
        int r = idx - l * (128 * 128);
        int nn = r >> 7;
        int k = r & 127;
        w2t[idx] = f2bf(W2[(size_t)l * 128 * 128 + k * 128 + nn]);
    }
}

// ---------------- CSR build ----------------
__global__ void csr_zero_kernel(int* __restrict__ cnt) {
    int i = blockIdx.x * blockDim.x + threadIdx.x;
    if (i < Vc) cnt[i] = 0;
}

__global__ void csr_count_kernel(const int* __restrict__ src, const int* __restrict__ dst,
                                 int* __restrict__ cnt) {
    int i = blockIdx.x * blockDim.x + threadIdx.x;
    if (i >= 2 * Ec) return;
    int v = (i < Ec) ? src[i] : dst[i - Ec];
    atomicAdd(&cnt[v], 1);
}

// single-block exclusive scan over Vc entries -> off[0..Vc], cur copy
__global__ void csr_scan_kernel(const int* __restrict__ cnt,
                                int* __restrict__ off, int* __restrict__ cur) {
    __shared__ int part[256];
    const int t = threadIdx.x;
    const int CH = (Vc + 255) / 256; // 49
    int s = 0;
    for (int j = 0; j < CH; ++j) {
        int i = t * CH + j;
        if (i < Vc) s += cnt[i];
    }
    part[t] = s;
    __syncthreads();
    for (int ofs = 1; ofs < 256; ofs <<= 1) {
        int y = (t >= ofs) ? part[t - ofs] : 0;
        __syncthreads();
        part[t] += y;
        __syncthreads();
    }
    int run = part[t] - s; // exclusive base for this chunk
    for (int j = 0; j < CH; ++j) {
        int i = t * CH + j;
        if (i < Vc) {
            off[i] = run;
            cur[i] = run;
            run += cnt[i];
        }
    }
    if (t == 255) off[Vc] = run;
}

__global__ void csr_fill_kernel(const int* __restrict__ src, const int* __restrict__ dst,
                                int* __restrict__ cur, int* __restrict__ adj) {
    int i = blockIdx.x * blockDim.x + threadIdx.x;
    if (i >= 2 * Ec) return;
    int e = (i < Ec) ? i : (i - Ec);
    int v = (i < Ec) ? src[e] : dst[e];
    int p = atomicAdd(&cur[v], 1);
    adj[p] = e;
}

// ---------------- gather edges -> vertices ----------------
// one wave per (b, v); lanes own 2 channels; writes vf as bf16
__global__ void gather_kernel(const float* __restrict__ h,
                              const int* __restrict__ off, const int* __restrict__ adj,
                              short* __restrict__ vf) {
    int gw = blockIdx.x * 4 + (threadIdx.x >> 6);
    if (gw >= Bc * Vc) return;
    int b = (gw >= Vc) ? 1 : 0;
    int v = gw - b * Vc;
    int lane = threadIdx.x & 63;
    int o0 = off[v], o1 = off[v + 1];
    const float2* hb = (const float2*)(h + (size_t)b * Ec * Dc);
    float2 acc = make_float2(0.f, 0.f);
    for (int j = o0; j < o1; ++j) {
        int e = adj[j];
        float2 x = hb[(size_t)e * (Dc / 2) + lane];
        acc.x += x.x;
        acc.y += x.y;
    }
    short2 w;
    w.x = f2bf(acc.x);
    w.y = f2bf(acc.y);
    ((short2*)vf)[(size_t)gw * (Dc / 2) + lane] = w;
}

// ---------------- fused edge MLP layer (MFMA bf16, barrier-free) ----------------
// 256 threads = 4 waves, 64 edges/block, 16 edges per wave (wave-private).
// GEMM1 B-frags load DIRECTLY from global vf (L2-resident) into registers;
// only x1 goes through LDS (wave-private rows -> no __syncthreads at all;
// DS ops are in-order within a wave).
#define X1STR 136  // x1s row stride (bf16): 128 + 8 pad (272B = 17*16B, conflict-balanced)
__launch_bounds__(256, 4)
__global__ void edge_layer_kernel(float* __restrict__ h,
                                  const short* __restrict__ vf,
                                  const int* __restrict__ src, const int* __restrict__ dst,
                                  const short* __restrict__ w1t, const float* __restrict__ b1,
                                  const float* __restrict__ ln_g, const float* __restrict__ ln_b,
                                  const short* __restrict__ w2t, const float* __restrict__ b2,
                                  const float* __restrict__ ng, const float* __restrict__ nb) {
    __shared__ __align__(16) short x1s[64][X1STR];

    const int t = threadIdx.x;
    const int w = t >> 6;
    const int lane = t & 63;
    const int m0 = w * 16;          // wave's edge sub-tile
    const int r = lane & 15;
    const int g = lane >> 4;        // k-block / reg-group

    const int eg = blockIdx.x * 64 + m0 + r;    // this lane's edge row
    const int b = (eg >= Ec) ? 1 : 0;
    const int e = eg - b * Ec;
    const int vs = src[e], vd = dst[e];
    const short* srow = vf + ((size_t)(b * Vc + vs)) * Dc;
    const short* drow = vf + ((size_t)(b * Vc + vd)) * Dc;

    // ---- GEMM1t: x1^T = W1^T (128x256) @ x^T (256x16), x = [vf[src]|vf[dst]]
    f32x4 acc[8];
    #pragma unroll
    for (int nt = 0; nt < 8; ++nt) acc[nt] = (f32x4){0.f, 0.f, 0.f, 0.f};
    short8s bfr[8];
    #pragma unroll
    for (int ks = 0; ks < 4; ++ks) bfr[ks] = *(const short8s*)(srow + 32 * ks + 8 * g);
    #pragma unroll
    for (int ks = 0; ks < 4; ++ks) bfr[4 + ks] = *(const short8s*)(drow + 32 * ks + 8 * g);
    #pragma unroll
    for (int ks = 0; ks < 8; ++ks) {
        #pragma unroll
        for (int nt = 0; nt < 8; ++nt) {
            short8s afrag = *(const short8s*)(w1t + (size_t)(nt * 16 + r) * 256 + 32 * ks + 8 * g);
            acc[nt] = mfma16(afrag, bfr[ks], acc[nt]);
        }
    }

    // ---- bias + LN + silu; repack to bf16 LDS (wave-private rows, no barrier)
    {
        float s = 0.f, ss = 0.f;
        #pragma unroll
        for (int nt = 0; nt < 8; ++nt) {
            const float4 bb = *(const float4*)&b1[nt * 16 + 4 * g];
            acc[nt][0] += bb.x; acc[nt][1] += bb.y; acc[nt][2] += bb.z; acc[nt][3] += bb.w;
            #pragma unroll
            for (int i = 0; i < 4; ++i) { float v = acc[nt][i]; s += v; ss += v * v; }
        }
        s += __shfl_xor(s, 16); ss += __shfl_xor(ss, 16);
        s += __shfl_xor(s, 32); ss += __shfl_xor(ss, 32);
        float mean = s * (1.0f / Dc);
        float var = ss * (1.0f / Dc) - mean * mean;
        float rstd = rsqrtf(var + 1e-5f);
        #pragma unroll
        for (int nt = 0; nt < 8; ++nt) {
            const float4 lg = *(const float4*)&ln_g[nt * 16 + 4 * g];
            const float4 lb = *(const float4*)&ln_b[nt * 16 + 4 * g];
            float o[4];
            #pragma unroll
            for (int i = 0; i < 4; ++i) {
                float gg = (i == 0) ? lg.x : (i == 1) ? lg.y : (i == 2) ? lg.z : lg.w;
                float bb = (i == 0) ? lb.x : (i == 1) ? lb.y : (i == 2) ? lb.z : lb.w;
                float xh = (acc[nt][i] - mean) * rstd * gg + bb;
                o[i] = xh / (1.0f + __expf(-xh));
            }
            short4 st;
            st.x = f2bf(o[0]); st.y = f2bf(o[1]); st.z = f2bf(o[2]); st.w = f2bf(o[3]);
            *(short4*)&x1s[m0 + r][nt * 16 + 4 * g] = st;
        }
    }
    // no __syncthreads: rows m0..m0+15 written & read only by this wave,
    // and DS ops within a wave execute in order.

    // ---- GEMM2t: x2^T = W2^T (128x128) @ x1^T (128x16)
    f32x4 acc2[8];
    #pragma unroll
    for (int nt = 0; nt < 8; ++nt) acc2[nt] = (f32x4){0.f, 0.f, 0.f, 0.f};
    #pragma unroll
    for (int ks = 0; ks < 4; ++ks) {
        short8s bfrag = *(const short8s*)&x1s[m0 + r][32 * ks + 8 * g];
        #pragma unroll
        for (int nt = 0; nt < 8; ++nt) {
            short8s afrag = *(const short8s*)(w2t + (size_t)(nt * 16 + r) * 128 + 32 * ks + 8 * g);
            acc2[nt] = mfma16(afrag, bfrag, acc2[nt]);
        }
    }

    // ---- bias + residual + LN -> h
    {
        float* hrow = h + (size_t)eg * Dc;
        float s = 0.f, ss = 0.f;
        #pragma unroll
        for (int nt = 0; nt < 8; ++nt) {
            const float4 bb = *(const float4*)&b2[nt * 16 + 4 * g];
            const float4 hv = *(const float4*)(hrow + nt * 16 + 4 * g);
            acc2[nt][0] += bb.x + hv.x; acc2[nt][1] += bb.y + hv.y;
            acc2[nt][2] += bb.z + hv.z; acc2[nt][3] += bb.w + hv.w;
            #pragma unroll
            for (int i = 0; i < 4; ++i) { float v = acc2[nt][i]; s += v; ss += v * v; }
        }
        s += __shfl_xor(s, 16); ss += __shfl_xor(ss, 16);
        s += __shfl_xor(s, 32); ss += __shfl_xor(ss, 32);
        float mean = s * (1.0f / Dc);
        float var = ss * (1.0f / Dc) - mean * mean;
        float rstd = rsqrtf(var + 1e-5f);
        #pragma unroll
        for (int nt = 0; nt < 8; ++nt) {
            const float4 gv = *(const float4*)&ng[nt * 16 + 4 * g];
            const float4 bv = *(const float4*)&nb[nt * 16 + 4 * g];
            float4 o;
            o.x = (acc2[nt][0] - mean) * rstd * gv.x + bv.x;
            o.y = (acc2[nt][1] - mean) * rstd * gv.y + bv.y;
            o.z = (acc2[nt][2] - mean) * rstd * gv.z + bv.z;
            o.w = (acc2[nt][3] - mean) * rstd * gv.w + bv.w;
            *(float4*)(hrow + nt * 16 + 4 * g) = o;
        }
    }
}

// ---------------- output projection ----------------
__global__ void out_proj_kernel(const float* __restrict__ h,
                                const float* __restrict__ w_out, const float* __restrict__ b_out,
                                float* __restrict__ out) {
    int be = blockIdx.x * blockDim.x + threadIdx.x;
    if (be >= Bc * Ec) return;
    const float4* hp = (const float4*)(h + (size_t)be * Dc);
    float a0 = b_out[0], a1 = b_out[1], a2 = b_out[2];
    for (int q = 0; q < Dc / 4; ++q) {
        float4 v = hp[q];
        int k = q * 4;
        a0 += v.x * w_out[(k + 0) * 3 + 0] + v.y * w_out[(k + 1) * 3 + 0] +
              v.z * w_out[(k + 2) * 3 + 0] + v.w * w_out[(k + 3) * 3 + 0];
        a1 += v.x * w_out[(k + 0) * 3 + 1] + v.y * w_out[(k + 1) * 3 + 1] +
              v.z * w_out[(k + 2) * 3 + 1] + v.w * w_out[(k + 3) * 3 + 1];
        a2 += v.x * w_out[(k + 0) * 3 + 2] + v.y * w_out[(k + 1) * 3 + 2] +
              v.z * w_out[(k + 2) * 3 + 2] + v.w * w_out[(k + 3) * 3 + 2];
    }
    out[be * 3 + 0] = a0;
    out[be * 3 + 1] = a1;
    out[be * 3 + 2] = a2;
}

extern "C" void kernel_launch(void* const* d_in, const int* in_sizes, int n_in,
                              void* d_out, int out_size, void* d_ws, size_t ws_size,
                              hipStream_t stream) {
    const float* delta = (const float*)d_in[0];
    const int* n = (const int*)d_in[1];
    const int* edge_index = (const int*)d_in[2];
    const float* w_in = (const float*)d_in[4];
    const float* b_in = (const float*)d_in[5];
    const float* W1 = (const float*)d_in[6];
    const float* b1 = (const float*)d_in[7];
    const float* ln_g = (const float*)d_in[8];
    const float* ln_b = (const float*)d_in[9];
    const float* W2 = (const float*)d_in[10];
    const float* b2 = (const float*)d_in[11];
    const float* ng = (const float*)d_in[12];
    const float* nb = (const float*)d_in[13];
    const float* te_w1 = (const float*)d_in[14];
    const float* te_b1 = (const float*)d_in[15];
    const float* te_w2 = (const float*)d_in[16];
    const float* te_b2 = (const float*)d_in[17];
    const float* w_out = (const float*)d_in[18];
    const float* b_out = (const float*)d_in[19];
    float* out = (float*)d_out;

    // ---- workspace layout (all 256B-aligned) ----
    char* ws = (char*)d_ws;
    size_t o = 0;
    float* t_emb = (float*)(ws + o); o += 1024;
    float* h     = (float*)(ws + o); o += (size_t)Bc * Ec * Dc * 4;        // 102.4 MB
    short* vf    = (short*)(ws + o); o += (size_t)Bc * Vc * Dc * 2;        // 6.4 MB
    short* w1t   = (short*)(ws + o); o += (size_t)Lc * 128 * 256 * 2;
    short* w2t   = (short*)(ws + o); o += (size_t)Lc * 128 * 128 * 2;
    int* cnt     = (int*)(ws + o);   o += ((size_t)Vc * 4 + 255) / 256 * 256;
    int* off     = (int*)(ws + o);   o += ((size_t)(Vc + 1) * 4 + 255) / 256 * 256;
    int* cur     = (int*)(ws + o);   o += ((size_t)Vc * 4 + 255) / 256 * 256;
    int* adj     = (int*)(ws + o);   o += (size_t)2 * Ec * 4;              // 800 KB

    const int* src = edge_index;
    const int* dst = edge_index + Ec;

    t_emb_kernel<<<Bc, Dc, 0, stream>>>(n, te_w1, te_b1, te_w2, te_b2, t_emb);
    convert_w_kernel<<<(Lc * 128 * 256 + 255) / 256, 256, 0, stream>>>(W1, W2, w1t, w2t);

    {
        int total = Bc * Ec * (Dc / 4);
        input_proj_kernel<<<(total + 255) / 256, 256, 0, stream>>>(delta, w_in, b_in, t_emb, h);
    }

    // CSR build (once per call)
    csr_zero_kernel<<<(Vc + 255) / 256, 256, 0, stream>>>(cnt);
    csr_count_kernel<<<(2 * Ec + 255) / 256, 256, 0, stream>>>(src, dst, cnt);
    csr_scan_kernel<<<1, 256, 0, stream>>>(cnt, off, cur);
    csr_fill_kernel<<<(2 * Ec + 255) / 256, 256, 0, stream>>>(src, dst, cur, adj);

    for (int i = 0; i < Lc; ++i) {
        gather_kernel<<<(Bc * Vc + 3) / 4, 256, 0, stream>>>(h, off, adj, vf);
        edge_layer_kernel<<<(Bc * Ec) / 64, 256, 0, stream>>>(
            h, vf, src, dst,
            w1t + (size_t)i * 128 * 256, b1 + i * Dc,
            ln_g + i * Dc, ln_b + i * Dc,
            w2t + (size_t)i * 128 * 128, b2 + i * Dc,
            ng + i * Dc, nb + i * Dc);
    }

    out_proj_kernel<<<(Bc * Ec + 255) / 256, 256, 0, stream>>>(h, w_out, b_out, out);
}

// Round 8
// 920.601 us; speedup vs baseline: 1.2650x; 1.2650x over previous
//
#include <hip/hip_runtime.h>
#include <math.h>

#define Bc 2
#define Ec 100000
#define Vc 12500
#define Dc 128
#define Lc 4

typedef __attribute__((ext_vector_type(4))) float f32x4;
typedef __attribute__((ext_vector_type(8))) short short8s;
typedef __attribute__((ext_vector_type(8))) __bf16 bf16x8;

static __device__ __forceinline__ short f2bf(float f) {
    unsigned u = __builtin_bit_cast(unsigned, f);
    unsigned r = (u + 0x7FFFu + ((u >> 16) & 1u)) >> 16;  // RNE
    return (short)r;
}

static __device__ __forceinline__ f32x4 mfma16(short8s a, short8s b, f32x4 c) {
    return __builtin_amdgcn_mfma_f32_16x16x32_bf16(
        __builtin_bit_cast(bf16x8, a), __builtin_bit_cast(bf16x8, b), c, 0, 0, 0);
}

// ---------------- timestep embedding MLP (tiny: B=2) ----------------
__global__ void t_emb_kernel(const int* __restrict__ n,
                             const float* __restrict__ te_w1, const float* __restrict__ te_b1,
                             const float* __restrict__ te_w2, const float* __restrict__ te_b2,
                             float* __restrict__ t_emb) {
    const int b = blockIdx.x;
    const int t = threadIdx.x; // 128 threads
    __shared__ float emb[Dc];
    __shared__ float hid[4 * Dc];
    const float nf = (float)n[b];
    const int half = Dc / 2;
    {
        int j = (t < half) ? t : (t - half);
        float freq = expf(-logf(10000.0f) * (float)j / (float)half);
        float arg = nf * freq;
        emb[t] = (t < half) ? sinf(arg) : cosf(arg);
    }
    __syncthreads();
    for (int jj = 0; jj < 4; ++jj) {
        int c = t + jj * Dc;
        float acc = te_b1[c];
        for (int k = 0; k < Dc; ++k) acc += emb[k] * te_w1[k * (4 * Dc) + c];
        hid[c] = acc / (1.0f + expf(-acc));
    }
    __syncthreads();
    float acc = te_b2[t];
    for (int k = 0; k < 4 * Dc; ++k) acc += hid[k] * te_w2[k * Dc + t];
    t_emb[b * Dc + t] = acc;
}

// ---------------- input projection + t_emb add ----------------
__global__ void input_proj_kernel(const float* __restrict__ delta,
                                  const float* __restrict__ w_in, const float* __restrict__ b_in,
                                  const float* __restrict__ t_emb,
                                  float* __restrict__ h) {
    int idx = blockIdx.x * blockDim.x + threadIdx.x;
    const int total = Bc * Ec * (Dc / 4);
    if (idx >= total) return;
    int dq = idx & (Dc / 4 - 1);
    int be = idx >> 5;
    int b = be / Ec;
    const float* dd = delta + (size_t)be * 3;
    float d0 = dd[0], d1 = dd[1], d2 = dd[2];
    float4 acc = ((const float4*)b_in)[dq];
    float4 te = ((const float4*)t_emb)[b * (Dc / 4) + dq];
    float4 w0 = ((const float4*)w_in)[dq];
    float4 w1 = ((const float4*)w_in)[(Dc / 4) + dq];
    float4 w2 = ((const float4*)w_in)[2 * (Dc / 4) + dq];
    acc.x += te.x + d0 * w0.x + d1 * w1.x + d2 * w2.x;
    acc.y += te.y + d0 * w0.y + d1 * w1.y + d2 * w2.y;
    acc.z += te.z + d0 * w0.z + d1 * w1.z + d2 * w2.z;
    acc.w += te.w + d0 * w0.w + d1 * w1.w + d2 * w2.w;
    ((float4*)h)[idx] = acc;
}

// ---------------- weight pre-convert: fp32 -> bf16 transposed ----------------
__global__ void convert_w_kernel(const float* __restrict__ W1, const float* __restrict__ W2,
                                 short* __restrict__ w1t, short* __restrict__ w2t) {
    int idx = blockIdx.x * blockDim.x + threadIdx.x;
    if (idx < Lc * 128 * 256) {
        int l = idx / (128 * 256);
        int r = idx - l * (128 * 256);
        int nn = r >> 8;          // 0..127
        int k = r & 255;          // 0..255
        w1t[idx] = f2bf(W1[(size_t)l * 256 * 128 + k * 128 + nn]);
    }
    if (idx < Lc * 128 * 128) {
        int l = idx / (128 * 128);
        int r = idx - l * (128 * 128);
        int nn = r >> 7;
        int k = r & 127;
        w2t[idx] = f2bf(W2[(size_t)l * 128 * 128 + k * 128 + nn]);
    }
}

// ---------------- CSR build ----------------
__global__ void csr_zero_kernel(int* __restrict__ cnt) {
    int i = blockIdx.x * blockDim.x + threadIdx.x;
    if (i < Vc) cnt[i] = 0;
}

__global__ void csr_count_kernel(const int* __restrict__ src, const int* __restrict__ dst,
                                 int* __restrict__ cnt) {
    int i = blockIdx.x * blockDim.x + threadIdx.x;
    if (i >= 2 * Ec) return;
    int v = (i < Ec) ? src[i] : dst[i - Ec];
    atomicAdd(&cnt[v], 1);
}

// single-block exclusive scan over Vc entries -> off[0..Vc], cur copy
__global__ void csr_scan_kernel(const int* __restrict__ cnt,
                                int* __restrict__ off, int* __restrict__ cur) {
    __shared__ int part[256];
    const int t = threadIdx.x;
    const int CH = (Vc + 255) / 256; // 49
    int s = 0;
    for (int j = 0; j < CH; ++j) {
        int i = t * CH + j;
        if (i < Vc) s += cnt[i];
    }
    part[t] = s;
    __syncthreads();
    for (int ofs = 1; ofs < 256; ofs <<= 1) {
        int y = (t >= ofs) ? part[t - ofs] : 0;
        __syncthreads();
        part[t] += y;
        __syncthreads();
    }
    int run = part[t] - s; // exclusive base for this chunk
    for (int j = 0; j < CH; ++j) {
        int i = t * CH + j;
        if (i < Vc) {
            off[i] = run;
            cur[i] = run;
            run += cnt[i];
        }
    }
    if (t == 255) off[Vc] = run;
}

__global__ void csr_fill_kernel(const int* __restrict__ src, const int* __restrict__ dst,
                                int* __restrict__ cur, int* __restrict__ adj) {
    int i = blockIdx.x * blockDim.x + threadIdx.x;
    if (i >= 2 * Ec) return;
    int e = (i < Ec) ? i : (i - Ec);
    int v = (i < Ec) ? src[e] : dst[e];
    int p = atomicAdd(&cur[v], 1);
    adj[p] = e;
}

// ---------------- gather edges -> vertices ----------------
// one wave per (b, v); lanes own 2 channels; writes vf as bf16
__global__ void gather_kernel(const float* __restrict__ h,
                              const int* __restrict__ off, const int* __restrict__ adj,
                              short* __restrict__ vf) {
    int gw = blockIdx.x * 4 + (threadIdx.x >> 6);
    if (gw >= Bc * Vc) return;
    int b = (gw >= Vc) ? 1 : 0;
    int v = gw - b * Vc;
    int lane = threadIdx.x & 63;
    int o0 = off[v], o1 = off[v + 1];
    const float2* hb = (const float2*)(h + (size_t)b * Ec * Dc);
    float2 acc = make_float2(0.f, 0.f);
    for (int j = o0; j < o1; ++j) {
        int e = adj[j];
        float2 x = hb[(size_t)e * (Dc / 2) + lane];
        acc.x += x.x;
        acc.y += x.y;
    }
    short2 w;
    w.x = f2bf(acc.x);
    w.y = f2bf(acc.y);
    ((short2*)vf)[(size_t)gw * (Dc / 2) + lane] = w;
}

// ---------------- fused edge MLP layer (MFMA bf16, 2 m-tiles/wave) ----------------
// 256 threads = 4 waves; each wave owns 32 edges = two 16-edge m-tiles.
// Every weight afrag is reused by 2 MFMAs (halves weight traffic, doubles ILP).
// vf b-frags software double-buffered across the ks loop.
#define X1STR 136  // x1s row stride (bf16): 128 + 8 pad
__launch_bounds__(256, 3)
__global__ void edge_layer_kernel(float* __restrict__ h,
                                  const short* __restrict__ vf,
                                  const int* __restrict__ src, const int* __restrict__ dst,
                                  const short* __restrict__ w1t, const float* __restrict__ b1,
                                  const float* __restrict__ ln_g, const float* __restrict__ ln_b,
                                  const short* __restrict__ w2t, const float* __restrict__ b2,
                                  const float* __restrict__ ng, const float* __restrict__ nb) {
    __shared__ __align__(16) short x1s[128][X1STR];

    const int t = threadIdx.x;
    const int w = t >> 6;
    const int lane = t & 63;
    const int r = lane & 15;
    const int g = lane >> 4;
    const int wavebase = (blockIdx.x * 4 + w) * 32;
    if (wavebase >= Bc * Ec) return;

    // edge rows for the two m-tiles
    int eg0 = wavebase + r;
    int eg1 = wavebase + 16 + r;
    const short *srow[2], *drow[2];
    {
        int bb0 = (eg0 >= Ec) ? 1 : 0;
        int e0 = eg0 - bb0 * Ec;
        srow[0] = vf + ((size_t)(bb0 * Vc + src[e0])) * Dc;
        drow[0] = vf + ((size_t)(bb0 * Vc + dst[e0])) * Dc;
        int bb1 = (eg1 >= Ec) ? 1 : 0;
        int e1 = eg1 - bb1 * Ec;
        srow[1] = vf + ((size_t)(bb1 * Vc + src[e1])) * Dc;
        drow[1] = vf + ((size_t)(bb1 * Vc + dst[e1])) * Dc;
    }

    // ---- GEMM1t: x1^T = W1^T (128x256) @ x^T (256x32), x = [vf[src]|vf[dst]]
    f32x4 acc[2][8];
    #pragma unroll
    for (int mt = 0; mt < 2; ++mt)
        #pragma unroll
        for (int nt = 0; nt < 8; ++nt) acc[mt][nt] = (f32x4){0.f, 0.f, 0.f, 0.f};

    short8s bcur0, bcur1, bnxt0, bnxt1;
    bcur0 = *(const short8s*)(srow[0] + 8 * g);
    bcur1 = *(const short8s*)(srow[1] + 8 * g);
    #pragma unroll
    for (int ks = 0; ks < 8; ++ks) {
        if (ks < 7) {
            int ksn = ks + 1;
            const short* p0 = (ksn < 4) ? srow[0] : drow[0];
            const short* p1 = (ksn < 4) ? srow[1] : drow[1];
            int kk = ksn & 3;
            bnxt0 = *(const short8s*)(p0 + 32 * kk + 8 * g);
            bnxt1 = *(const short8s*)(p1 + 32 * kk + 8 * g);
        }
        #pragma unroll
        for (int nt = 0; nt < 8; ++nt) {
            short8s afrag = *(const short8s*)(w1t + (size_t)(nt * 16 + r) * 256 + 32 * ks + 8 * g);
            acc[0][nt] = mfma16(afrag, bcur0, acc[0][nt]);
            acc[1][nt] = mfma16(afrag, bcur1, acc[1][nt]);
        }
        bcur0 = bnxt0;
        bcur1 = bnxt1;
    }

    // ---- bias + LN + silu; repack to bf16 LDS (wave-private rows, no barrier)
    #pragma unroll
    for (int mt = 0; mt < 2; ++mt) {
        float s = 0.f, ss = 0.f;
        #pragma unroll
        for (int nt = 0; nt < 8; ++nt) {
            const float4 bb = *(const float4*)&b1[nt * 16 + 4 * g];
            acc[mt][nt][0] += bb.x; acc[mt][nt][1] += bb.y;
            acc[mt][nt][2] += bb.z; acc[mt][nt][3] += bb.w;
            #pragma unroll
            for (int i = 0; i < 4; ++i) { float v = acc[mt][nt][i]; s += v; ss += v * v; }
        }
        s += __shfl_xor(s, 16); ss += __shfl_xor(ss, 16);
        s += __shfl_xor(s, 32); ss += __shfl_xor(ss, 32);
        float mean = s * (1.0f / Dc);
        float var = ss * (1.0f / Dc) - mean * mean;
        float rstd = rsqrtf(var + 1e-5f);
        const int lrow = w * 32 + mt * 16 + r;
        #pragma unroll
        for (int nt = 0; nt < 8; ++nt) {
            const float4 lg = *(const float4*)&ln_g[nt * 16 + 4 * g];
            const float4 lb = *(const float4*)&ln_b[nt * 16 + 4 * g];
            float o[4];
            #pragma unroll
            for (int i = 0; i < 4; ++i) {
                float gg = (i == 0) ? lg.x : (i == 1) ? lg.y : (i == 2) ? lg.z : lg.w;
                float bb = (i == 0) ? lb.x : (i == 1) ? lb.y : (i == 2) ? lb.z : lb.w;
                float xh = (acc[mt][nt][i] - mean) * rstd * gg + bb;
                o[i] = xh / (1.0f + __expf(-xh));
            }
            short4 st;
            st.x = f2bf(o[0]); st.y = f2bf(o[1]); st.z = f2bf(o[2]); st.w = f2bf(o[3]);
            *(short4*)&x1s[lrow][nt * 16 + 4 * g] = st;
        }
    }
    // no __syncthreads: x1s rows are wave-private; DS ops in-order within a wave.

    // ---- GEMM2t: x2^T = W2^T (128x128) @ x1^T (128x32)
    f32x4 acc2[2][8];
    #pragma unroll
    for (int mt = 0; mt < 2; ++mt)
        #pragma unroll
        for (int nt = 0; nt < 8; ++nt) acc2[mt][nt] = (f32x4){0.f, 0.f, 0.f, 0.f};
    #pragma unroll
    for (int ks = 0; ks < 4; ++ks) {
        short8s bf0 = *(const short8s*)&x1s[w * 32 + r][32 * ks + 8 * g];
        short8s bf1 = *(const short8s*)&x1s[w * 32 + 16 + r][32 * ks + 8 * g];
        #pragma unroll
        for (int nt = 0; nt < 8; ++nt) {
            short8s afrag = *(const short8s*)(w2t + (size_t)(nt * 16 + r) * 128 + 32 * ks + 8 * g);
            acc2[0][nt] = mfma16(afrag, bf0, acc2[0][nt]);
            acc2[1][nt] = mfma16(afrag, bf1, acc2[1][nt]);
        }
    }

    // ---- bias + residual + LN -> h  (per m-tile)
    #pragma unroll
    for (int mt = 0; mt < 2; ++mt) {
        const int eg = wavebase + mt * 16 + r;
        float* hrow = h + (size_t)eg * Dc;
        float s = 0.f, ss = 0.f;
        #pragma unroll
        for (int nt = 0; nt < 8; ++nt) {
            const float4 bb = *(const float4*)&b2[nt * 16 + 4 * g];
            const float4 hv = *(const float4*)(hrow + nt * 16 + 4 * g);
            acc2[mt][nt][0] += bb.x + hv.x; acc2[mt][nt][1] += bb.y + hv.y;
            acc2[mt][nt][2] += bb.z + hv.z; acc2[mt][nt][3] += bb.w + hv.w;
            #pragma unroll
            for (int i = 0; i < 4; ++i) { float v = acc2[mt][nt][i]; s += v; ss += v * v; }
        }
        s += __shfl_xor(s, 16); ss += __shfl_xor(ss, 16);
        s += __shfl_xor(s, 32); ss += __shfl_xor(ss, 32);
        float mean = s * (1.0f / Dc);
        float var = ss * (1.0f / Dc) - mean * mean;
        float rstd = rsqrtf(var + 1e-5f);
        #pragma unroll
        for (int nt = 0; nt < 8; ++nt) {
            const float4 gv = *(const float4*)&ng[nt * 16 + 4 * g];
            const float4 bv = *(const float4*)&nb[nt * 16 + 4 * g];
            float4 o;
            o.x = (acc2[mt][nt][0] - mean) * rstd * gv.x + bv.x;
            o.y = (acc2[mt][nt][1] - mean) * rstd * gv.y + bv.y;
            o.z = (acc2[mt][nt][2] - mean) * rstd * gv.z + bv.z;
            o.w = (acc2[mt][nt][3] - mean) * rstd * gv.w + bv.w;
            *(float4*)(hrow + nt * 16 + 4 * g) = o;
        }
    }
}

// ---------------- output projection ----------------
__global__ void out_proj_kernel(const float* __restrict__ h,
                                const float* __restrict__ w_out, const float* __restrict__ b_out,
                                float* __restrict__ out) {
    int be = blockIdx.x * blockDim.x + threadIdx.x;
    if (be >= Bc * Ec) return;
    const float4* hp = (const float4*)(h + (size_t)be * Dc);
    float a0 = b_out[0], a1 = b_out[1], a2 = b_out[2];
    for (int q = 0; q < Dc / 4; ++q) {
        float4 v = hp[q];
        int k = q * 4;
        a0 += v.x * w_out[(k + 0) * 3 + 0] + v.y * w_out[(k + 1) * 3 + 0] +
              v.z * w_out[(k + 2) * 3 + 0] + v.w * w_out[(k + 3) * 3 + 0];
        a1 += v.x * w_out[(k + 0) * 3 + 1] + v.y * w_out[(k + 1) * 3 + 1] +
              v.z * w_out[(k + 2) * 3 + 1] + v.w * w_out[(k + 3) * 3 + 1];
        a2 += v.x * w_out[(k + 0) * 3 + 2] + v.y * w_out[(k + 1) * 3 + 2] +
              v.z * w_out[(k + 2) * 3 + 2] + v.w * w_out[(k + 3) * 3 + 2];
    }
    out[be * 3 + 0] = a0;
    out[be * 3 + 1] = a1;
    out[be * 3 + 2] = a2;
}

extern "C" void kernel_launch(void* const* d_in, const int* in_sizes, int n_in,
                              void* d_out, int out_size, void* d_ws, size_t ws_size,
                              hipStream_t stream) {
    const float* delta = (const float*)d_in[0];
    const int* n = (const int*)d_in[1];
    const int* edge_index = (const int*)d_in[2];
    const float* w_in = (const float*)d_in[4];
    const float* b_in = (const float*)d_in[5];
    const float* W1 = (const float*)d_in[6];
    const float* b1 = (const float*)d_in[7];
    const float* ln_g = (const float*)d_in[8];
    const float* ln_b = (const float*)d_in[9];
    const float* W2 = (const float*)d_in[10];
    const float* b2 = (const float*)d_in[11];
    const float* ng = (const float*)d_in[12];
    const float* nb = (const float*)d_in[13];
    const float* te_w1 = (const float*)d_in[14];
    const float* te_b1 = (const float*)d_in[15];
    const float* te_w2 = (const float*)d_in[16];
    const float* te_b2 = (const float*)d_in[17];
    const float* w_out = (const float*)d_in[18];
    const float* b_out = (const float*)d_in[19];
    float* out = (float*)d_out;

    // ---- workspace layout (all 256B-aligned) ----
    char* ws = (char*)d_ws;
    size_t o = 0;
    float* t_emb = (float*)(ws + o); o += 1024;
    float* h     = (float*)(ws + o); o += (size_t)Bc * Ec * Dc * 4;        // 102.4 MB
    short* vf    = (short*)(ws + o); o += (size_t)Bc * Vc * Dc * 2;        // 6.4 MB
    short* w1t   = (short*)(ws + o); o += (size_t)Lc * 128 * 256 * 2;
    short* w2t   = (short*)(ws + o); o += (size_t)Lc * 128 * 128 * 2;
    int* cnt     = (int*)(ws + o);   o += ((size_t)Vc * 4 + 255) / 256 * 256;
    int* off     = (int*)(ws + o);   o += ((size_t)(Vc + 1) * 4 + 255) / 256 * 256;
    int* cur     = (int*)(ws + o);   o += ((size_t)Vc * 4 + 255) / 256 * 256;
    int* adj     = (int*)(ws + o);   o += (size_t)2 * Ec * 4;              // 800 KB

    const int* src = edge_index;
    const int* dst = edge_index + Ec;

    t_emb_kernel<<<Bc, Dc, 0, stream>>>(n, te_w1, te_b1, te_w2, te_b2, t_emb);
    convert_w_kernel<<<(Lc * 128 * 256 + 255) / 256, 256, 0, stream>>>(W1, W2, w1t, w2t);

    {
        int total = Bc * Ec * (Dc / 4);
        input_proj_kernel<<<(total + 255) / 256, 256, 0, stream>>>(delta, w_in, b_in, t_emb, h);
    }

    // CSR build (once per call)
    csr_zero_kernel<<<(Vc + 255) / 256, 256, 0, stream>>>(cnt);
    csr_count_kernel<<<(2 * Ec + 255) / 256, 256, 0, stream>>>(src, dst, cnt);
    csr_scan_kernel<<<1, 256, 0, stream>>>(cnt, off, cur);
    csr_fill_kernel<<<(2 * Ec + 255) / 256, 256, 0, stream>>>(src, dst, cur, adj);

    const int eblocks = (Bc * Ec + 127) / 128;   // 4 waves x 32 edges per block
    for (int i = 0; i < Lc; ++i) {
        gather_kernel<<<(Bc * Vc + 3) / 4, 256, 0, stream>>>(h, off, adj, vf);
        edge_layer_kernel<<<eblocks, 256, 0, stream>>>(
            h, vf, src, dst,
            w1t + (size_t)i * 128 * 256, b1 + i * Dc,
            ln_g + i * Dc, ln_b + i * Dc,
            w2t + (size_t)i * 128 * 128, b2 + i * Dc,
            ng + i * Dc, nb + i * Dc);
    }

    out_proj_kernel<<<(Bc * Ec + 255) / 256, 256, 0, stream>>>(h, w_out, b_out, out);
}

// Round 9
// 742.568 us; speedup vs baseline: 1.5683x; 1.2398x over previous
//
#include <hip/hip_runtime.h>
#include <math.h>

#define Bc 2
#define Ec 100000
#define Vc 12500
#define Dc 128
#define Lc 4

typedef __attribute__((ext_vector_type(4))) float f32x4;
typedef __attribute__((ext_vector_type(8))) short short8s;
typedef __attribute__((ext_vector_type(8))) __bf16 bf16x8;

static __device__ __forceinline__ short f2bf(float f) {
    unsigned u = __builtin_bit_cast(unsigned, f);
    unsigned r = (u + 0x7FFFu + ((u >> 16) & 1u)) >> 16;  // RNE
    return (short)r;
}

static __device__ __forceinline__ f32x4 mfma16(short8s a, short8s b, f32x4 c) {
    return __builtin_amdgcn_mfma_f32_16x16x32_bf16(
        __builtin_bit_cast(bf16x8, a), __builtin_bit_cast(bf16x8, b), c, 0, 0, 0);
}

// swizzled byte offset into x1s: rows mod 8 spread across 8 16B slots (2-way = free)
#define SWZ(row, bytecol) ((((row) * 256) + (bytecol)) ^ (((row) & 7) << 4))

// ---------------- timestep embedding MLP (tiny: B=2) ----------------
__global__ void t_emb_kernel(const int* __restrict__ n,
                             const float* __restrict__ te_w1, const float* __restrict__ te_b1,
                             const float* __restrict__ te_w2, const float* __restrict__ te_b2,
                             float* __restrict__ t_emb) {
    const int b = blockIdx.x;
    const int t = threadIdx.x; // 128 threads
    __shared__ float emb[Dc];
    __shared__ float hid[4 * Dc];
    const float nf = (float)n[b];
    const int half = Dc / 2;
    {
        int j = (t < half) ? t : (t - half);
        float freq = expf(-logf(10000.0f) * (float)j / (float)half);
        float arg = nf * freq;
        emb[t] = (t < half) ? sinf(arg) : cosf(arg);
    }
    __syncthreads();
    for (int jj = 0; jj < 4; ++jj) {
        int c = t + jj * Dc;
        float acc = te_b1[c];
        for (int k = 0; k < Dc; ++k) acc += emb[k] * te_w1[k * (4 * Dc) + c];
        hid[c] = acc / (1.0f + expf(-acc));
    }
    __syncthreads();
    float acc = te_b2[t];
    for (int k = 0; k < 4 * Dc; ++k) acc += hid[k] * te_w2[k * Dc + t];
    t_emb[b * Dc + t] = acc;
}

// ---------------- input projection + t_emb add ----------------
__global__ void input_proj_kernel(const float* __restrict__ delta,
                                  const float* __restrict__ w_in, const float* __restrict__ b_in,
                                  const float* __restrict__ t_emb,
                                  float* __restrict__ h) {
    int idx = blockIdx.x * blockDim.x + threadIdx.x;
    const int total = Bc * Ec * (Dc / 4);
    if (idx >= total) return;
    int dq = idx & (Dc / 4 - 1);
    int be = idx >> 5;
    int b = be / Ec;
    const float* dd = delta + (size_t)be * 3;
    float d0 = dd[0], d1 = dd[1], d2 = dd[2];
    float4 acc = ((const float4*)b_in)[dq];
    float4 te = ((const float4*)t_emb)[b * (Dc / 4) + dq];
    float4 w0 = ((const float4*)w_in)[dq];
    float4 w1 = ((const float4*)w_in)[(Dc / 4) + dq];
    float4 w2 = ((const float4*)w_in)[2 * (Dc / 4) + dq];
    acc.x += te.x + d0 * w0.x + d1 * w1.x + d2 * w2.x;
    acc.y += te.y + d0 * w0.y + d1 * w1.y + d2 * w2.y;
    acc.z += te.z + d0 * w0.z + d1 * w1.z + d2 * w2.z;
    acc.w += te.w + d0 * w0.w + d1 * w1.w + d2 * w2.w;
    ((float4*)h)[idx] = acc;
}

// ---------------- weight pre-convert: fp32 -> bf16 fragment-major ----------------
// w1f[l][ks(8)][nt(8)][lane(64)][j(8)]  elem = W1[l][k][n], n = nt*16 + (lane&15),
//   k = 32*ks + 8*(lane>>4) + j   -> one wave afrag load = contiguous 1KB
// w2f[l][ks(4)][nt(8)][lane(64)][j(8)]  same with k over 128
__global__ void convert_w_kernel(const float* __restrict__ W1, const float* __restrict__ W2,
                                 short* __restrict__ w1f, short* __restrict__ w2f) {
    int idx = blockIdx.x * blockDim.x + threadIdx.x;
    if (idx < Lc * 32768) {
        int l = idx >> 15;
        int rm = idx & 32767;
        int j = rm & 7;
        int lane = (rm >> 3) & 63;
        int nt = (rm >> 9) & 7;
        int ks = (rm >> 12) & 7;
        int r = lane & 15, g = lane >> 4;
        int n = nt * 16 + r;
        int k = 32 * ks + 8 * g + j;
        w1f[idx] = f2bf(W1[((size_t)l * 256 + k) * 128 + n]);
    }
    if (idx < Lc * 16384) {
        int l = idx >> 14;
        int rm = idx & 16383;
        int j = rm & 7;
        int lane = (rm >> 3) & 63;
        int nt = (rm >> 9) & 7;
        int ks = (rm >> 12) & 3;
        int r = lane & 15, g = lane >> 4;
        int n = nt * 16 + r;
        int k = 32 * ks + 8 * g + j;
        w2f[idx] = f2bf(W2[((size_t)l * 128 + k) * 128 + n]);
    }
}

// ---------------- CSR build ----------------
__global__ void csr_zero_kernel(int* __restrict__ cnt) {
    int i = blockIdx.x * blockDim.x + threadIdx.x;
    if (i < Vc) cnt[i] = 0;
}

__global__ void csr_count_kernel(const int* __restrict__ src, const int* __restrict__ dst,
                                 int* __restrict__ cnt) {
    int i = blockIdx.x * blockDim.x + threadIdx.x;
    if (i >= 2 * Ec) return;
    int v = (i < Ec) ? src[i] : dst[i - Ec];
    atomicAdd(&cnt[v], 1);
}

__global__ void csr_scan_kernel(const int* __restrict__ cnt,
                                int* __restrict__ off, int* __restrict__ cur) {
    __shared__ int part[256];
    const int t = threadIdx.x;
    const int CH = (Vc + 255) / 256; // 49
    int s = 0;
    for (int j = 0; j < CH; ++j) {
        int i = t * CH + j;
        if (i < Vc) s += cnt[i];
    }
    part[t] = s;
    __syncthreads();
    for (int ofs = 1; ofs < 256; ofs <<= 1) {
        int y = (t >= ofs) ? part[t - ofs] : 0;
        __syncthreads();
        part[t] += y;
        __syncthreads();
    }
    int run = part[t] - s;
    for (int j = 0; j < CH; ++j) {
        int i = t * CH + j;
        if (i < Vc) {
            off[i] = run;
            cur[i] = run;
            run += cnt[i];
        }
    }
    if (t == 255) off[Vc] = run;
}

__global__ void csr_fill_kernel(const int* __restrict__ src, const int* __restrict__ dst,
                                int* __restrict__ cur, int* __restrict__ adj) {
    int i = blockIdx.x * blockDim.x + threadIdx.x;
    if (i >= 2 * Ec) return;
    int e = (i < Ec) ? i : (i - Ec);
    int v = (i < Ec) ? src[e] : dst[e];
    int p = atomicAdd(&cur[v], 1);
    adj[p] = e;
}

// ---------------- gather edges -> vertices ----------------
// one wave per (b, v); lanes own 2 channels; unroll-4 row loads; writes vf as bf16
__global__ void gather_kernel(const float* __restrict__ h,
                              const int* __restrict__ off, const int* __restrict__ adj,
                              short* __restrict__ vf) {
    int gw = blockIdx.x * 4 + (threadIdx.x >> 6);
    if (gw >= Bc * Vc) return;
    int b = (gw >= Vc) ? 1 : 0;
    int v = gw - b * Vc;
    int lane = threadIdx.x & 63;
    int o0 = off[v], o1 = off[v + 1];
    const float2* hb = (const float2*)(h + (size_t)b * Ec * Dc);
    float2 a0 = make_float2(0.f, 0.f), a1 = a0, a2 = a0, a3 = a0;
    int j = o0;
    for (; j + 4 <= o1; j += 4) {
        int e0 = adj[j], e1 = adj[j + 1], e2 = adj[j + 2], e3 = adj[j + 3];
        float2 x0 = hb[(size_t)e0 * 64 + lane];
        float2 x1 = hb[(size_t)e1 * 64 + lane];
        float2 x2 = hb[(size_t)e2 * 64 + lane];
        float2 x3 = hb[(size_t)e3 * 64 + lane];
        a0.x += x0.x; a0.y += x0.y;
        a1.x += x1.x; a1.y += x1.y;
        a2.x += x2.x; a2.y += x2.y;
        a3.x += x3.x; a3.y += x3.y;
    }
    for (; j < o1; ++j) {
        int e = adj[j];
        float2 x = hb[(size_t)e * 64 + lane];
        a0.x += x.x; a0.y += x.y;
    }
    float sx = (a0.x + a1.x) + (a2.x + a3.x);
    float sy = (a0.y + a1.y) + (a2.y + a3.y);
    short2 w;
    w.x = f2bf(sx);
    w.y = f2bf(sy);
    ((short2*)vf)[(size_t)gw * (Dc / 2) + lane] = w;
}

// ---------------- fused edge MLP layer (MFMA bf16, 4 m-tiles/wave) ----------------
// 256 threads = 4 waves; each wave owns 64 edges = four 16-edge m-tiles.
// Weight afrags (fragment-major, coalesced 1KB/instr) reused by 4 MFMAs each.
// x1 round-trips through XOR-swizzled unpadded LDS (wave-private rows, no barriers).
// Last layer: fuse output projection, skip h store.
__launch_bounds__(256, 2)
__global__ void edge_layer_kernel(float* __restrict__ h,
                                  const short* __restrict__ vf,
                                  const int* __restrict__ src, const int* __restrict__ dst,
                                  const short* __restrict__ w1f, const float* __restrict__ b1,
                                  const float* __restrict__ ln_g, const float* __restrict__ ln_b,
                                  const short* __restrict__ w2f, const float* __restrict__ b2,
                                  const float* __restrict__ ng, const float* __restrict__ nb,
                                  const float* __restrict__ w_out, const float* __restrict__ b_out,
                                  float* __restrict__ out) {
    __shared__ __align__(16) short x1s[256 * 128];   // 64 KB, swizzled access
    char* x1b = (char*)x1s;

    const int t = threadIdx.x;
    const int w = t >> 6;
    const int lane = t & 63;
    const int r = lane & 15;
    const int g = lane >> 4;
    const int wavebase = (blockIdx.x * 4 + w) * 64;
    if (wavebase >= Bc * Ec) return;
    const int wloc = w * 64;

    // row pointers for the 4 m-tiles
    const short *srow[4], *drow[4];
    #pragma unroll
    for (int mt = 0; mt < 4; ++mt) {
        int eg = wavebase + mt * 16 + r;
        int bb = (eg >= Ec) ? 1 : 0;
        int e = eg - bb * Ec;
        srow[mt] = vf + ((size_t)(bb * Vc + src[e])) * Dc;
        drow[mt] = vf + ((size_t)(bb * Vc + dst[e])) * Dc;
    }

    // ---- GEMM1t: x1^T = W1^T (128x256) @ x^T (256x64), x = [vf[src]|vf[dst]]
    f32x4 acc[4][8];
    #pragma unroll
    for (int mt = 0; mt < 4; ++mt)
        #pragma unroll
        for (int nt = 0; nt < 8; ++nt) acc[mt][nt] = (f32x4){0.f, 0.f, 0.f, 0.f};

    short8s bcur[4], bnxt[4];
    #pragma unroll
    for (int mt = 0; mt < 4; ++mt) bcur[mt] = *(const short8s*)(srow[mt] + 8 * g);
    #pragma unroll
    for (int ks = 0; ks < 8; ++ks) {
        if (ks < 7) {
            int ksn = ks + 1;
            int kk = ksn & 3;
            #pragma unroll
            for (int mt = 0; mt < 4; ++mt) {
                const short* p = (ksn < 4) ? srow[mt] : drow[mt];
                bnxt[mt] = *(const short8s*)(p + 32 * kk + 8 * g);
            }
        }
        #pragma unroll
        for (int nt = 0; nt < 8; ++nt) {
            short8s afrag = *(const short8s*)(w1f + ((size_t)(ks * 8 + nt) * 64 + lane) * 8);
            acc[0][nt] = mfma16(afrag, bcur[0], acc[0][nt]);
            acc[1][nt] = mfma16(afrag, bcur[1], acc[1][nt]);
            acc[2][nt] = mfma16(afrag, bcur[2], acc[2][nt]);
            acc[3][nt] = mfma16(afrag, bcur[3], acc[3][nt]);
        }
        #pragma unroll
        for (int mt = 0; mt < 4; ++mt) bcur[mt] = bnxt[mt];
    }

    // ---- bias + LN + silu; repack to swizzled bf16 LDS (wave-private, no barrier)
    #pragma unroll
    for (int mt = 0; mt < 4; ++mt) {
        float s = 0.f, ss = 0.f;
        #pragma unroll
        for (int nt = 0; nt < 8; ++nt) {
            const float4 bb = *(const float4*)&b1[nt * 16 + 4 * g];
            acc[mt][nt][0] += bb.x; acc[mt][nt][1] += bb.y;
            acc[mt][nt][2] += bb.z; acc[mt][nt][3] += bb.w;
            #pragma unroll
            for (int i = 0; i < 4; ++i) { float v = acc[mt][nt][i]; s += v; ss += v * v; }
        }
        s += __shfl_xor(s, 16); ss += __shfl_xor(ss, 16);
        s += __shfl_xor(s, 32); ss += __shfl_xor(ss, 32);
        float mean = s * (1.0f / Dc);
        float var = ss * (1.0f / Dc) - mean * mean;
        float rstd = rsqrtf(var + 1e-5f);
        const int lrow = wloc + mt * 16 + r;
        #pragma unroll
        for (int nt = 0; nt < 8; ++nt) {
            const float4 lg = *(const float4*)&ln_g[nt * 16 + 4 * g];
            const float4 lb = *(const float4*)&ln_b[nt * 16 + 4 * g];
            float o[4];
            #pragma unroll
            for (int i = 0; i < 4; ++i) {
                float gg = (i == 0) ? lg.x : (i == 1) ? lg.y : (i == 2) ? lg.z : lg.w;
                float bb = (i == 0) ? lb.x : (i == 1) ? lb.y : (i == 2) ? lb.z : lb.w;
                float xh = (acc[mt][nt][i] - mean) * rstd * gg + bb;
                o[i] = xh / (1.0f + __expf(-xh));
            }
            short4 st;
            st.x = f2bf(o[0]); st.y = f2bf(o[1]); st.z = f2bf(o[2]); st.w = f2bf(o[3]);
            *(short4*)(x1b + SWZ(lrow, (nt * 16 + 4 * g) * 2)) = st;
        }
    }
    // no __syncthreads: x1s rows are wave-private; DS ops in-order within a wave.

    // ---- GEMM2t: x2^T = W2^T (128x128) @ x1^T (128x64)
    f32x4 acc2[4][8];
    #pragma unroll
    for (int mt = 0; mt < 4; ++mt)
        #pragma unroll
        for (int nt = 0; nt < 8; ++nt) acc2[mt][nt] = (f32x4){0.f, 0.f, 0.f, 0.f};
    #pragma unroll
    for (int ks = 0; ks < 4; ++ks) {
        short8s bf[4];
        #pragma unroll
        for (int mt = 0; mt < 4; ++mt) {
            const int lrow = wloc + mt * 16 + r;
            bf[mt] = *(const short8s*)(x1b + SWZ(lrow, (32 * ks + 8 * g) * 2));
        }
        #pragma unroll
        for (int nt = 0; nt < 8; ++nt) {
            short8s afrag = *(const short8s*)(w2f + ((size_t)(ks * 8 + nt) * 64 + lane) * 8);
            acc2[0][nt] = mfma16(afrag, bf[0], acc2[0][nt]);
            acc2[1][nt] = mfma16(afrag, bf[1], acc2[1][nt]);
            acc2[2][nt] = mfma16(afrag, bf[2], acc2[2][nt]);
            acc2[3][nt] = mfma16(afrag, bf[3], acc2[3][nt]);
        }
    }

    // ---- bias + residual + LN -> h (or fused out-proj on last layer)
    const bool last = (w_out != nullptr);
    #pragma unroll
    for (int mt = 0; mt < 4; ++mt) {
        const int eg = wavebase + mt * 16 + r;
        float* hrow = h + (size_t)eg * Dc;
        float s = 0.f, ss = 0.f;
        #pragma unroll
        for (int nt = 0; nt < 8; ++nt) {
            const float4 bb = *(const float4*)&b2[nt * 16 + 4 * g];
            const float4 hv = *(const float4*)(hrow + nt * 16 + 4 * g);
            acc2[mt][nt][0] += bb.x + hv.x; acc2[mt][nt][1] += bb.y + hv.y;
            acc2[mt][nt][2] += bb.z + hv.z; acc2[mt][nt][3] += bb.w + hv.w;
            #pragma unroll
            for (int i = 0; i < 4; ++i) { float v = acc2[mt][nt][i]; s += v; ss += v * v; }
        }
        s += __shfl_xor(s, 16); ss += __shfl_xor(ss, 16);
        s += __shfl_xor(s, 32); ss += __shfl_xor(ss, 32);
        float mean = s * (1.0f / Dc);
        float var = ss * (1.0f / Dc) - mean * mean;
        float rstd = rsqrtf(var + 1e-5f);
        if (!last) {
            #pragma unroll
            for (int nt = 0; nt < 8; ++nt) {
                const float4 gv = *(const float4*)&ng[nt * 16 + 4 * g];
                const float4 bv = *(const float4*)&nb[nt * 16 + 4 * g];
                float4 o;
                o.x = (acc2[mt][nt][0] - mean) * rstd * gv.x + bv.x;
                o.y = (acc2[mt][nt][1] - mean) * rstd * gv.y + bv.y;
                o.z = (acc2[mt][nt][2] - mean) * rstd * gv.z + bv.z;
                o.w = (acc2[mt][nt][3] - mean) * rstd * gv.w + bv.w;
                *(float4*)(hrow + nt * 16 + 4 * g) = o;
            }
        } else {
            // fused output projection: out[eg] = LN(...) @ w_out + b_out
            float a0 = 0.f, a1 = 0.f, a2 = 0.f;
            #pragma unroll
            for (int nt = 0; nt < 8; ++nt) {
                const float4 gv = *(const float4*)&ng[nt * 16 + 4 * g];
                const float4 bv = *(const float4*)&nb[nt * 16 + 4 * g];
                #pragma unroll
                for (int i = 0; i < 4; ++i) {
                    float gg = (i == 0) ? gv.x : (i == 1) ? gv.y : (i == 2) ? gv.z : gv.w;
                    float bb = (i == 0) ? bv.x : (i == 1) ? bv.y : (i == 2) ? bv.z : bv.w;
                    float y = (acc2[mt][nt][i] - mean) * rstd * gg + bb;
                    int nidx = nt * 16 + 4 * g + i;
                    a0 += y * w_out[nidx * 3 + 0];
                    a1 += y * w_out[nidx * 3 + 1];
                    a2 += y * w_out[nidx * 3 + 2];
                }
            }
            a0 += __shfl_xor(a0, 16); a1 += __shfl_xor(a1, 16); a2 += __shfl_xor(a2, 16);
            a0 += __shfl_xor(a0, 32); a1 += __shfl_xor(a1, 32); a2 += __shfl_xor(a2, 32);
            if (g == 0) {
                out[(size_t)eg * 3 + 0] = a0 + b_out[0];
                out[(size_t)eg * 3 + 1] = a1 + b_out[1];
                out[(size_t)eg * 3 + 2] = a2 + b_out[2];
            }
        }
    }
}

extern "C" void kernel_launch(void* const* d_in, const int* in_sizes, int n_in,
                              void* d_out, int out_size, void* d_ws, size_t ws_size,
                              hipStream_t stream) {
    const float* delta = (const float*)d_in[0];
    const int* n = (const int*)d_in[1];
    const int* edge_index = (const int*)d_in[2];
    const float* w_in = (const float*)d_in[4];
    const float* b_in = (const float*)d_in[5];
    const float* W1 = (const float*)d_in[6];
    const float* b1 = (const float*)d_in[7];
    const float* ln_g = (const float*)d_in[8];
    const float* ln_b = (const float*)d_in[9];
    const float* W2 = (const float*)d_in[10];
    const float* b2 = (const float*)d_in[11];
    const float* ng = (const float*)d_in[12];
    const float* nb = (const float*)d_in[13];
    const float* te_w1 = (const float*)d_in[14];
    const float* te_b1 = (const float*)d_in[15];
    const float* te_w2 = (const float*)d_in[16];
    const float* te_b2 = (const float*)d_in[17];
    const float* w_out = (const float*)d_in[18];
    const float* b_out = (const float*)d_in[19];
    float* out = (float*)d_out;

    // ---- workspace layout (all 256B-aligned) ----
    char* ws = (char*)d_ws;
    size_t o = 0;
    float* t_emb = (float*)(ws + o); o += 1024;
    float* h     = (float*)(ws + o); o += (size_t)Bc * Ec * Dc * 4;        // 102.4 MB
    short* vf    = (short*)(ws + o); o += (size_t)Bc * Vc * Dc * 2;        // 6.4 MB
    short* w1f   = (short*)(ws + o); o += (size_t)Lc * 32768 * 2;
    short* w2f   = (short*)(ws + o); o += (size_t)Lc * 16384 * 2;
    int* cnt     = (int*)(ws + o);   o += ((size_t)Vc * 4 + 255) / 256 * 256;
    int* off     = (int*)(ws + o);   o += ((size_t)(Vc + 1) * 4 + 255) / 256 * 256;
    int* cur     = (int*)(ws + o);   o += ((size_t)Vc * 4 + 255) / 256 * 256;
    int* adj     = (int*)(ws + o);   o += (size_t)2 * Ec * 4;              // 800 KB

    const int* src = edge_index;
    const int* dst = edge_index + Ec;

    t_emb_kernel<<<Bc, Dc, 0, stream>>>(n, te_w1, te_b1, te_w2, te_b2, t_emb);
    convert_w_kernel<<<(Lc * 32768 + 255) / 256, 256, 0, stream>>>(W1, W2, w1f, w2f);

    {
        int total = Bc * Ec * (Dc / 4);
        input_proj_kernel<<<(total + 255) / 256, 256, 0, stream>>>(delta, w_in, b_in, t_emb, h);
    }

    // CSR build (once per call)
    csr_zero_kernel<<<(Vc + 255) / 256, 256, 0, stream>>>(cnt);
    csr_count_kernel<<<(2 * Ec + 255) / 256, 256, 0, stream>>>(src, dst, cnt);
    csr_scan_kernel<<<1, 256, 0, stream>>>(cnt, off, cur);
    csr_fill_kernel<<<(2 * Ec + 255) / 256, 256, 0, stream>>>(src, dst, cur, adj);

    const int eblocks = (Bc * Ec + 255) / 256;   // 4 waves x 64 edges per block
    for (int i = 0; i < Lc; ++i) {
        gather_kernel<<<(Bc * Vc + 3) / 4, 256, 0, stream>>>(h, off, adj, vf);
        edge_layer_kernel<<<eblocks, 256, 0, stream>>>(
            h, vf, src, dst,
            w1f + (size_t)i * 32768, b1 + i * Dc,
            ln_g + i * Dc, ln_b + i * Dc,
            w2f + (size_t)i * 16384, b2 + i * Dc,
            ng + i * Dc, nb + i * Dc,
            (i == Lc - 1) ? w_out : nullptr, b_out, out);
    }
}